// Round 1
// baseline (642.565 us; speedup 1.0000x reference)
//
#include <hip/hip_runtime.h>

#define T_LEN 1024
#define NS 128

// Barrier that drains only LDS ops (lgkmcnt), leaving global prefetch loads
// (vmcnt) in flight across the barrier. __syncthreads() would emit
// s_waitcnt vmcnt(0) lgkmcnt(0) and serialize the unary prefetch every step.
__device__ __forceinline__ void sync_lds_only() {
    asm volatile("s_waitcnt lgkmcnt(0)" ::: "memory");
    __builtin_amdgcn_s_barrier();
}

__launch_bounds__(256, 1)
__global__ void crf_fwd_kernel(const float* __restrict__ unary,
                               const float* __restrict__ trans,
                               const int* __restrict__ lengths,
                               float* __restrict__ out) {
    __shared__ float fbuf[2][NS];   // ping-pong scaled-prob vector f = exp(alpha - C)
    __shared__ float wpart[4];

    const int b    = blockIdx.x;
    const int tid  = threadIdx.x;
    const int w    = tid >> 6;        // wave 0..3
    const int lane = tid & 63;
    const int sub  = lane >> 5;       // which half of j-range
    const int li   = lane & 31;
    const int i    = (w << 5) + li;   // owned state row

    // E[i][j] = exp(trans[i][j]) for this thread's 64-wide j half, in registers.
    float Erow[64];
    {
        const float4* tv = (const float4*)(trans + i * NS + (sub << 6));
        #pragma unroll
        for (int k = 0; k < 16; ++k) {
            float4 c = tv[k];
            Erow[4 * k + 0] = __expf(c.x);
            Erow[4 * k + 1] = __expf(c.y);
            Erow[4 * k + 2] = __expf(c.z);
            Erow[4 * k + 3] = __expf(c.w);
        }
    }
    const float Eend = __expf(trans[2 * NS + i]);   // END_IDX = 2 row

    // init: alpha_0 = NEG_INF except START_IDX=1 -> f = one-hot at 1, C = 0
    if (tid < NS) fbuf[0][tid] = (tid == 1) ? 1.0f : 0.0f;

    const int len = lengths[b];      // >= 1 by construction
    const float* ub = unary + ((size_t)b * T_LEN) * NS + i;

    // depth-2 unary prefetch pipeline (rows t and t+1 always exist, T=1024)
    float u_c = ub[0];
    float u_n = ub[NS];
    __syncthreads();

    float C = 0.0f;
    float f_last = 1.0f;

    for (int t = 0; t < len; ++t) {
        const float* fb = fbuf[t & 1];
        float* gb = (float*)fbuf[(t + 1) & 1];

        // prefetch unary row t+2 (clamped; stays in flight across the barrier)
        int tp = t + 2; tp = (tp < T_LEN) ? tp : (T_LEN - 1);
        float u_n2 = ub[(size_t)tp * NS];

        // 64-wide half-dot: acc = sum_j E[i][j] * f[j], broadcast LDS reads
        const float4* fv = (const float4*)(fb + (sub << 6));
        float4 c0 = *(const float4*)fb;   // f[0..3]: normalizer source
        float a0 = 0.f, a1 = 0.f, a2 = 0.f, a3 = 0.f;
        #pragma unroll
        for (int k = 0; k < 16; ++k) {
            float4 c = fv[k];
            a0 = fmaf(Erow[4 * k + 0], c.x, a0);
            a1 = fmaf(Erow[4 * k + 1], c.y, a1);
            a2 = fmaf(Erow[4 * k + 2], c.z, a2);
            a3 = fmaf(Erow[4 * k + 3], c.w, a3);
        }
        float acc = (a0 + a1) + (a2 + a3);
        acc += __shfl_xor(acc, 32, 64);   // combine the two j-halves in-wave

        // same-step scalar normalizer (uniform across all threads)
        float s4 = (c0.x + c0.y) + (c0.z + c0.w);
        C += __logf(s4);
        float fn = __fdividef(acc * __expf(u_c), s4);
        if (sub == 0) gb[i] = fn;
        f_last = fn;

        u_c = u_n; u_n = u_n2;
        sync_lds_only();
    }

    // terminal: out[b] = C + log( sum_i f_last[i] * exp(trans[END][i]) )
    float term = (sub == 0) ? f_last * Eend : 0.0f;
    #pragma unroll
    for (int d = 1; d < 64; d <<= 1) term += __shfl_xor(term, d, 64);
    if (lane == 0) wpart[w] = term;
    __syncthreads();
    if (tid == 0) {
        out[b] = C + __logf((wpart[0] + wpart[1]) + (wpart[2] + wpart[3]));
    }
}

extern "C" void kernel_launch(void* const* d_in, const int* in_sizes, int n_in,
                              void* d_out, int out_size, void* d_ws, size_t ws_size,
                              hipStream_t stream) {
    const float* unary   = (const float*)d_in[0];
    const float* trans   = (const float*)d_in[1];
    const int*   lengths = (const int*)d_in[2];
    float* out = (float*)d_out;

    const int B = in_sizes[2];   // 256
    crf_fwd_kernel<<<dim3(B), dim3(256), 0, stream>>>(unary, trans, lengths, out);
}

// Round 2
// 619.258 us; speedup vs baseline: 1.0376x; 1.0376x over previous
//
#include <hip/hip_runtime.h>

#define T_LEN 1024
#define NS    128
#define BT    16    // batches per group (MFMA N dim)
#define FSTR  144   // bf16 LDS row stride in shorts (288 B, 16B-aligned rows)
#define USF   132   // fp32 U-tile row stride in floats (528 B, 16B-aligned)

typedef __attribute__((ext_vector_type(8))) short short8;
typedef __attribute__((ext_vector_type(4))) short short4v;
typedef __attribute__((ext_vector_type(4))) float f32x4;

static __device__ __forceinline__ short f2bf(float f) {   // f32 -> bf16 (RNE)
    unsigned u = __builtin_bit_cast(unsigned, f);
    u = (u + 0x7fffu + ((u >> 16) & 1u)) >> 16;
    return (short)u;
}
static __device__ __forceinline__ float bf2f(short s) {
    unsigned u = ((unsigned)(unsigned short)s) << 16;
    return __builtin_bit_cast(float, u);
}

// exp(unary) -> bf16, rearranged to group-tiled layout:
// euw[((g*T + t)*16 + r)*128 + i]  so each (g,t) tile is 4 KiB contiguous.
__global__ __launch_bounds__(256) void expu_prepass(const float* __restrict__ unary,
                                                    short* __restrict__ euw) {
    int n = blockIdx.x * 256 + threadIdx.x;   // one 8-element chunk
    int i8 = n & 15, r = (n >> 4) & 15, t = (n >> 8) & (T_LEN - 1), g = n >> 18;
    const float* src = unary + (((size_t)(g * BT + r) * T_LEN + t) * NS + i8 * 8);
    float4 a = *(const float4*)src;
    float4 b = *(const float4*)(src + 4);
    short8 o;
    o[0] = f2bf(__expf(a.x)); o[1] = f2bf(__expf(a.y));
    o[2] = f2bf(__expf(a.z)); o[3] = f2bf(__expf(a.w));
    o[4] = f2bf(__expf(b.x)); o[5] = f2bf(__expf(b.y));
    o[6] = f2bf(__expf(b.z)); o[7] = f2bf(__expf(b.w));
    *(short8*)(euw + (size_t)n * 8) = o;
}

// One block = one group of 16 batches. 4 waves; wave w owns output rows
// i in [w*32, w*32+32) as two 16x16 m-tiles. Per step:
//   D'[i,b] = sum_j E[i,j] * F[b,j]   (8x mfma_f32_16x16x32_bf16, E static in regs)
//   fn = D' * expu_t / s_b ;  s_b = sum F_prev[b,0..3]  (self-compensating: C += log s)
// D'-layout: row i = quad*4+reg, col b = lane&15 -> all per-lane LDS accesses contiguous.
template<int PRE>
__global__ __launch_bounds__(256, 1) void crf_mfma(
        const float* __restrict__ unary, const float* __restrict__ trans,
        const int* __restrict__ lengths, const short* __restrict__ euw,
        float* __restrict__ out) {
    __shared__ __align__(16) short Fs[2][BT][FSTR];   // bf16 scaled-prob matrix, dbuf
    __shared__ float term[BT], Cfin[BT];
    __shared__ int smax;
    __shared__ __align__(16) char Ubraw[PRE ? 2 * BT * FSTR * 2 : 2 * BT * USF * 4];
    typedef short UsT[BT][FSTR];
    typedef float UfT[BT][USF];
    UsT* Us = (UsT*)Ubraw;   // Us[buf][b][i] bf16 exp(unary) tile
    UfT* Uf = (UfT*)Ubraw;   // Uf[buf][b][i] fp32 raw unary tile (fallback)

    const int tid = threadIdx.x;
    const int w = tid >> 6, lane = tid & 63;
    const int quad = lane >> 4, bcol = lane & 15;
    const int g = blockIdx.x;

    // ---- init LDS ----
    if (tid == 0) smax = 0;
    {   // F_0 = one-hot at START_IDX=1 (exp of init alphas), C = 0
        int r = tid >> 4, c0 = (tid & 15) * 8;
        #pragma unroll
        for (int j = 0; j < 8; ++j)
            Fs[0][r][c0 + j] = (short)((c0 + j == 1) ? 0x3F80 : 0);
    }
    if (tid < BT) { term[tid] = 0.f; Cfin[tid] = 0.f; }
    __syncthreads();
    if (tid < BT) atomicMax(&smax, lengths[g * BT + tid]);

    // ---- per-lane constants ----
    const int len = lengths[g * BT + bcol];
    const int lenm1 = len - 1;
    const int ib0 = w * 32, ib1 = w * 32 + 16;    // m-tile row bases
    const int i00 = ib0 + quad * 4, i01 = ib1 + quad * 4;  // this lane's D rows

    // E = exp(trans) A-frags: A[m=lane&15][k=quad*8+j], m-tile mt, k-tile kt
    short8 Ea[2][4];
    #pragma unroll
    for (int mt = 0; mt < 2; ++mt) {
        const float* tr = trans + (size_t)((mt ? ib1 : ib0) + bcol) * NS + quad * 8;
        #pragma unroll
        for (int kt = 0; kt < 4; ++kt) {
            float4 x = *(const float4*)(tr + kt * 32);
            float4 y = *(const float4*)(tr + kt * 32 + 4);
            short8 e;
            e[0] = f2bf(__expf(x.x)); e[1] = f2bf(__expf(x.y));
            e[2] = f2bf(__expf(x.z)); e[3] = f2bf(__expf(x.w));
            e[4] = f2bf(__expf(y.x)); e[5] = f2bf(__expf(y.y));
            e[6] = f2bf(__expf(y.z)); e[7] = f2bf(__expf(y.w));
            Ea[mt][kt] = e;
        }
    }
    float EendV[2][4];   // exp(trans[END=2][i]) for this lane's 8 output rows
    #pragma unroll
    for (int mt = 0; mt < 2; ++mt) {
        float4 ee = *(const float4*)(trans + 2 * NS + (mt ? i01 : i00));
        EendV[mt][0] = __expf(ee.x); EendV[mt][1] = __expf(ee.y);
        EendV[mt][2] = __expf(ee.z); EendV[mt][3] = __expf(ee.w);
    }

    // ---- unary staging pipeline: regs hold tile t+1, LDS holds tile t ----
    const int urow = tid >> 4, ucol = (tid & 15) * 8;
    short8 uregs; float4 uregf0, uregf1;
    if (PRE) {
        const short* base = euw + (((size_t)g * T_LEN) << 11) + tid * 8;
        uregs = *(const short8*)base;              // tile 0
        *(short8*)&Us[0][urow][ucol] = uregs;
        uregs = *(const short8*)(base + 2048);     // tile 1 -> regs
    } else {
        const float* base = unary + (size_t)(g * BT + urow) * T_LEN * NS + ucol;
        uregf0 = *(const float4*)base;
        uregf1 = *(const float4*)(base + 4);
        *(float4*)&Uf[0][urow][ucol] = uregf0;
        *(float4*)&Uf[0][urow][ucol + 4] = uregf1;
        uregf0 = *(const float4*)(base + NS);
        uregf1 = *(const float4*)(base + NS + 4);
    }
    __syncthreads();
    const int tmax = smax;
    float C = 0.f;

    for (int t = 0; t < tmax; ++t) {
        const int cur = t & 1, nxt = cur ^ 1;

        // LDS reads first (feed MFMA asap). B[k=quad*8+j][n=bcol] = F[bcol][j]: contiguous.
        short8 Bf[4];
        #pragma unroll
        for (int kt = 0; kt < 4; ++kt)
            Bf[kt] = *(const short8*)&Fs[cur][bcol][kt * 32 + quad * 8];
        short4v s4 = *(const short4v*)&Fs[cur][bcol][0];

        short4v eu0s, eu1s; float4 euf0, euf1;
        if (PRE) {
            eu0s = *(const short4v*)&Us[cur][bcol][i00];
            eu1s = *(const short4v*)&Us[cur][bcol][i01];
        } else {
            euf0 = *(const float4*)&Uf[cur][bcol][i00];
            euf1 = *(const float4*)&Uf[cur][bcol][i01];
        }

        // stage tile t+1 -> other buffer; prefetch tile t+2 (stays in flight
        // across the LDS-only barrier; no vmcnt(0) drain per step)
        int t2 = t + 2; if (t2 > T_LEN - 1) t2 = T_LEN - 1;
        if (PRE) {
            *(short8*)&Us[nxt][urow][ucol] = uregs;
            uregs = *(const short8*)(euw + (((size_t)g * T_LEN + t2) << 11) + tid * 8);
        } else {
            *(float4*)&Uf[nxt][urow][ucol] = uregf0;
            *(float4*)&Uf[nxt][urow][ucol + 4] = uregf1;
            const float* base = unary + ((size_t)(g * BT + urow) * T_LEN + t2) * NS + ucol;
            uregf0 = *(const float4*)base;
            uregf1 = *(const float4*)(base + 4);
        }

        // D' = E * F^T over K=128
        f32x4 a0 = {0.f, 0.f, 0.f, 0.f}, a1 = {0.f, 0.f, 0.f, 0.f};
        #pragma unroll
        for (int kt = 0; kt < 4; ++kt) {
            a0 = __builtin_amdgcn_mfma_f32_16x16x32_bf16(Ea[0][kt], Bf[kt], a0, 0, 0, 0);
            a1 = __builtin_amdgcn_mfma_f32_16x16x32_bf16(Ea[1][kt], Bf[kt], a1, 0, 0, 0);
        }

        // normalizer from previous f (exact compensation: same s in C and division)
        float s = (bf2f(s4[0]) + bf2f(s4[1])) + (bf2f(s4[2]) + bf2f(s4[3]));
        float rs = __fdividef(1.f, s);
        C += __logf(s);

        float fn0[4], fn1[4];
        #pragma unroll
        for (int r = 0; r < 4; ++r) {
            float e0 = PRE ? bf2f(eu0s[r]) : __expf(((const float*)&euf0)[r]);
            float e1 = PRE ? bf2f(eu1s[r]) : __expf(((const float*)&euf1)[r]);
            fn0[r] = a0[r] * e0 * rs;
            fn1[r] = a1[r] * e1 * rs;
        }

        short4v p0, p1;
        #pragma unroll
        for (int r = 0; r < 4; ++r) { p0[r] = f2bf(fn0[r]); p1[r] = f2bf(fn1[r]); }
        *(short4v*)&Fs[nxt][bcol][i00] = p0;
        *(short4v*)&Fs[nxt][bcol][i01] = p1;

        // row b finishes at t == len_b-1: record terminal partial + C. Frozen
        // rows keep evolving afterwards (bounded, column-isolated) — harmless.
        if (t == lenm1) {
            float part = 0.f;
            #pragma unroll
            for (int r = 0; r < 4; ++r)
                part += fn0[r] * EendV[0][r] + fn1[r] * EendV[1][r];
            atomicAdd(&term[bcol], part);
            if (tid < BT) Cfin[tid] = C;   // tid<16 => w=0,quad=0,bcol=tid
        }

        asm volatile("s_waitcnt lgkmcnt(0)" ::: "memory");
        __builtin_amdgcn_s_barrier();
    }

    if (tid < BT) out[g * BT + tid] = Cfin[tid] + __logf(term[tid]);
}

extern "C" void kernel_launch(void* const* d_in, const int* in_sizes, int n_in,
                              void* d_out, int out_size, void* d_ws, size_t ws_size,
                              hipStream_t stream) {
    const float* unary   = (const float*)d_in[0];
    const float* trans   = (const float*)d_in[1];
    const int*   lengths = (const int*)d_in[2];
    float* out = (float*)d_out;

    const int B = in_sizes[2];          // 256
    const int G = B / BT;               // 16 groups
    size_t need = (size_t)B * T_LEN * NS * sizeof(short);  // 67 MB
    if (ws_size >= need) {
        short* euw = (short*)d_ws;
        int chunks = B * T_LEN * (NS / 8);
        expu_prepass<<<dim3(chunks / 256), dim3(256), 0, stream>>>(unary, euw);
        crf_mfma<1><<<dim3(G), dim3(256), 0, stream>>>(unary, trans, lengths, euw, out);
    } else {
        crf_mfma<0><<<dim3(G), dim3(256), 0, stream>>>(unary, trans, lengths, nullptr, out);
    }
}

// Round 3
// 443.729 us; speedup vs baseline: 1.4481x; 1.3956x over previous
//
#include <hip/hip_runtime.h>

#define T_LEN 1024
#define NS    128
#define BT    16    // batches per group
#define G     16    // groups (B=256)

typedef __attribute__((ext_vector_type(8))) short short8;
typedef __attribute__((ext_vector_type(4))) short short4v;
typedef __attribute__((ext_vector_type(4))) float f32x4;

static __device__ __forceinline__ short f2bf(float f) {   // RNE (one-time uses)
    unsigned u = __builtin_bit_cast(unsigned, f);
    u = (u + 0x7fffu + ((u >> 16) & 1u)) >> 16;
    return (short)u;
}
static __device__ __forceinline__ float bf2f(short s) {
    unsigned u = ((unsigned)(unsigned short)s) << 16;
    return __builtin_bit_cast(float, u);
}
static __device__ __forceinline__ short f2bf_trunc(float f) {  // in-loop: 1 op
    return (short)(__builtin_bit_cast(unsigned, f) >> 16);
}

// Blocks 0..15: forward half of group g (f-recurrence, records g_m = E f_m raw + C_f).
// Blocks 16..31: backward half (p-recurrence p <- eu_t (*) (E^T p), init eu_{len-1}(*)r,
// records p_m + C_b). Wall length per block ~ len/2. out = C_f + C_b + log(p.g).
__global__ __launch_bounds__(256, 1) void crf_half(
        const float* __restrict__ unary, const float* __restrict__ trans,
        const int* __restrict__ lengths, float* __restrict__ gv,
        float* __restrict__ pv, float* __restrict__ cf, float* __restrict__ cb) {
    // XOR-swizzled (16B chunk ^ row) tiles: conflict-free for all access patterns here.
    __shared__ __align__(16) short Fs[2][BT * NS];   // bf16 state, row=batch, 16 chunks/row
    __shared__ __align__(16) float Us[2][BT * NS];   // fp32 raw unary tile, 32 chunks/row
    __shared__ int lenS[BT];
    __shared__ int itersS;

    const int tid = threadIdx.x;
    const bool bwd = blockIdx.x >= G;
    const int g = blockIdx.x & (G - 1);
    const int w = tid >> 6, lane = tid & 63;
    const int quad = lane >> 4, bcol = lane & 15;
    const int sr = tid >> 4, sc = tid & 15;          // staging row / col-chunk

    if (tid == 0) itersS = 0;
    if (tid < BT) lenS[tid] = lengths[g * BT + tid];
    __syncthreads();
    if (tid < BT) {
        int L = lenS[tid], mm = (L - 1) >> 1;
        atomicMax(&itersS, bwd ? (L - 1 - mm) : (mm + 1));
    }

    const int len = lenS[bcol];
    const int m_b = (len - 1) >> 1;
    const int nrec = bwd ? (len - 2 - m_b) : m_b;    // -1 for bwd len==1 (init-recorded)
    const int slen = lenS[sr];

    // ---- A-fragments: E (fwd) or E^T (bwd), bf16, once ----
    short8 Ea[2][4];
    #pragma unroll
    for (int mt = 0; mt < 2; ++mt) {
        const int i = w * 32 + mt * 16 + bcol;       // A's m-index
        #pragma unroll
        for (int kt = 0; kt < 4; ++kt) {
            short8 e;
            if (!bwd) {
                const float* tr = trans + (size_t)i * NS + kt * 32 + quad * 8;
                float4 x = *(const float4*)tr, y = *(const float4*)(tr + 4);
                e[0] = f2bf(__expf(x.x)); e[1] = f2bf(__expf(x.y));
                e[2] = f2bf(__expf(x.z)); e[3] = f2bf(__expf(x.w));
                e[4] = f2bf(__expf(y.x)); e[5] = f2bf(__expf(y.y));
                e[6] = f2bf(__expf(y.z)); e[7] = f2bf(__expf(y.w));
            } else {
                #pragma unroll
                for (int jj = 0; jj < 8; ++jj)
                    e[jj] = f2bf(__expf(trans[(size_t)(kt * 32 + quad * 8 + jj) * NS + i]));
            }
            Ea[mt][kt] = e;
        }
    }

    // ---- state init into Fs[0] ----
    if (!bwd) {
        short8 z;
        #pragma unroll
        for (int k = 0; k < 8; ++k) z[k] = (short)((sc * 8 + k == 1) ? 0x3F80 : 0);
        *(short8*)&Fs[0][sr * NS + ((sc ^ sr) << 3)] = z;
    } else {
        const float* up = unary + ((size_t)(g * BT + sr) * T_LEN + (slen - 1)) * NS + sc * 8;
        float4 ua = *(const float4*)up, ub = *(const float4*)(up + 4);
        const float* t2 = trans + 2 * NS + sc * 8;
        float v[8];
        v[0] = __expf(ua.x + t2[0]); v[1] = __expf(ua.y + t2[1]);
        v[2] = __expf(ua.z + t2[2]); v[3] = __expf(ua.w + t2[3]);
        v[4] = __expf(ub.x + t2[4]); v[5] = __expf(ub.y + t2[5]);
        v[6] = __expf(ub.z + t2[6]); v[7] = __expf(ub.w + t2[7]);
        short8 z;
        #pragma unroll
        for (int k = 0; k < 8; ++k) z[k] = f2bf(v[k]);
        *(short8*)&Fs[0][sr * NS + ((sc ^ sr) << 3)] = z;
        if (slen == 1) {   // no iterations for this column: record the init state
            float* pp = pv + (size_t)(g * BT + sr) * NS + sc * 8;
            #pragma unroll
            for (int k = 0; k < 8; ++k) pp[k] = v[k];
            if (sc == 0) cb[g * BT + sr] = 0.f;
        }
    }

    // ---- unary staging: LDS holds tile n, regs hold tile n+1, prefetch n+2 ----
    const float* ubase = unary + (size_t)(g * BT + sr) * T_LEN * NS + sc * 8;
    const int u_off0 = sr * NS + (((2 * sc) ^ (sr & 7)) << 2);
    const int u_off1 = sr * NS + (((2 * sc + 1) ^ (sr & 7)) << 2);
    #define T_OF(n) ({ int _t = bwd ? (slen - 2 - (n)) : (n); \
                       _t = _t < 0 ? 0 : (_t > T_LEN - 1 ? T_LEN - 1 : _t); _t; })
    float4 ra0, ra1;
    {
        int t = T_OF(0);
        ra0 = *(const float4*)(ubase + (size_t)t * NS);
        ra1 = *(const float4*)(ubase + (size_t)t * NS + 4);
        *(float4*)&Us[0][u_off0] = ra0;
        *(float4*)&Us[0][u_off1] = ra1;
        t = T_OF(1);
        ra0 = *(const float4*)(ubase + (size_t)t * NS);
        ra1 = *(const float4*)(ubase + (size_t)t * NS + 4);
    }
    __syncthreads();
    const int iters = itersS;

    // loop-invariant LDS offsets (all conflict-free under the XOR swizzle)
    int bfOff[4];
    #pragma unroll
    for (int kt = 0; kt < 4; ++kt) bfOff[kt] = bcol * NS + (((kt * 4 + quad) ^ bcol) << 3);
    const int s4Off = bcol * NS + (bcol << 3);                       // logical chunk 0
    const int ur0 = bcol * NS + (((w * 8 + quad) ^ (bcol & 7)) << 2);
    const int ur1 = bcol * NS + (((w * 8 + 4 + quad) ^ (bcol & 7)) << 2);
    const int c0 = w * 4 + (quad >> 1), half = (quad & 1) << 2;      // F write chunks
    const int fw0 = bcol * NS + ((c0 ^ bcol) << 3) + half;
    const int fw1 = bcol * NS + (((c0 + 2) ^ bcol) << 3) + half;

    float C = 0.f;
    for (int n = 0; n < iters; ++n) {
        const int cur = n & 1, nxt = cur ^ 1;
        const short* fb = Fs[cur];
        short8 Bf0 = *(const short8*)&fb[bfOff[0]];
        short8 Bf1 = *(const short8*)&fb[bfOff[1]];
        short8 Bf2 = *(const short8*)&fb[bfOff[2]];
        short8 Bf3 = *(const short8*)&fb[bfOff[3]];
        short4v s4 = *(const short4v*)&fb[s4Off];
        float4 u0 = *(const float4*)&Us[cur][ur0];
        float4 u1 = *(const float4*)&Us[cur][ur1];

        // stage tile n+1, prefetch n+2 (global loads stay in flight across barrier)
        *(float4*)&Us[nxt][u_off0] = ra0;
        *(float4*)&Us[nxt][u_off1] = ra1;
        {
            int t = T_OF(n + 2);
            ra0 = *(const float4*)(ubase + (size_t)t * NS);
            ra1 = *(const float4*)(ubase + (size_t)t * NS + 4);
        }

        // matvec: two independent 2-deep MFMA chains per m-tile
        f32x4 x0 = {0.f,0.f,0.f,0.f}, y0 = {0.f,0.f,0.f,0.f};
        f32x4 x1 = {0.f,0.f,0.f,0.f}, y1 = {0.f,0.f,0.f,0.f};
        x0 = __builtin_amdgcn_mfma_f32_16x16x32_bf16(Ea[0][0], Bf0, x0, 0, 0, 0);
        x1 = __builtin_amdgcn_mfma_f32_16x16x32_bf16(Ea[1][0], Bf0, x1, 0, 0, 0);
        y0 = __builtin_amdgcn_mfma_f32_16x16x32_bf16(Ea[0][2], Bf2, y0, 0, 0, 0);
        y1 = __builtin_amdgcn_mfma_f32_16x16x32_bf16(Ea[1][2], Bf2, y1, 0, 0, 0);
        x0 = __builtin_amdgcn_mfma_f32_16x16x32_bf16(Ea[0][1], Bf1, x0, 0, 0, 0);
        x1 = __builtin_amdgcn_mfma_f32_16x16x32_bf16(Ea[1][1], Bf1, x1, 0, 0, 0);
        y0 = __builtin_amdgcn_mfma_f32_16x16x32_bf16(Ea[0][3], Bf3, y0, 0, 0, 0);
        y1 = __builtin_amdgcn_mfma_f32_16x16x32_bf16(Ea[1][3], Bf3, y1, 0, 0, 0);
        f32x4 a0 = x0 + y0, a1 = x1 + y1;

        // per-column normalizer from stored state (exact compensation via C += log s)
        float s = (bf2f(s4[0]) + bf2f(s4[1])) + (bf2f(s4[2]) + bf2f(s4[3]));
        float rs = __fdividef(1.f, s);
        float logs = __logf(s);
        float e0[4], e1[4];
        e0[0] = __expf(u0.x); e0[1] = __expf(u0.y); e0[2] = __expf(u0.z); e0[3] = __expf(u0.w);
        e1[0] = __expf(u1.x); e1[1] = __expf(u1.y); e1[2] = __expf(u1.z); e1[3] = __expf(u1.w);
        float fn0[4], fn1[4];
        #pragma unroll
        for (int r = 0; r < 4; ++r) {
            fn0[r] = a0[r] * e0[r] * rs;
            fn1[r] = a1[r] * e1[r] * rs;
        }

        if (!bwd) {
            if (n == nrec) {   // g_m = E f_m raw (pre-eu, pre-norm), C before update
                float* gp = gv + (size_t)(g * BT + bcol) * NS;
                *(float4*)(gp + w * 32 + quad * 4)      = (float4){a0[0], a0[1], a0[2], a0[3]};
                *(float4*)(gp + w * 32 + 16 + quad * 4) = (float4){a1[0], a1[1], a1[2], a1[3]};
                if (tid < BT) cf[g * BT + tid] = C;
            }
            C += logs;
        } else {
            C += logs;
            if (n == nrec) {   // p_m after full step, C after update
                float* pp = pv + (size_t)(g * BT + bcol) * NS;
                *(float4*)(pp + w * 32 + quad * 4)      = (float4){fn0[0], fn0[1], fn0[2], fn0[3]};
                *(float4*)(pp + w * 32 + 16 + quad * 4) = (float4){fn1[0], fn1[1], fn1[2], fn1[3]};
                if (tid < BT) cb[g * BT + tid] = C;
            }
        }

        short4v p0, p1;
        #pragma unroll
        for (int r = 0; r < 4; ++r) { p0[r] = f2bf_trunc(fn0[r]); p1[r] = f2bf_trunc(fn1[r]); }
        *(short4v*)&Fs[nxt][fw0] = p0;
        *(short4v*)&Fs[nxt][fw1] = p1;

        // LDS-only barrier: keeps the global unary prefetch in flight
        asm volatile("s_waitcnt lgkmcnt(0)" ::: "memory");
        __builtin_amdgcn_s_barrier();
    }
}

__global__ __launch_bounds__(64) void crf_combine(
        const float* __restrict__ gv, const float* __restrict__ pv,
        const float* __restrict__ cf, const float* __restrict__ cb,
        float* __restrict__ out) {
    const int b = blockIdx.x, lane = threadIdx.x;
    const float* gp = gv + (size_t)b * NS;
    const float* pp = pv + (size_t)b * NS;
    float d = gp[lane] * pp[lane] + gp[lane + 64] * pp[lane + 64];
    #pragma unroll
    for (int off = 1; off < 64; off <<= 1) d += __shfl_xor(d, off, 64);
    if (lane == 0) out[b] = cf[b] + cb[b] + __logf(d);
}

extern "C" void kernel_launch(void* const* d_in, const int* in_sizes, int n_in,
                              void* d_out, int out_size, void* d_ws, size_t ws_size,
                              hipStream_t stream) {
    const float* unary   = (const float*)d_in[0];
    const float* trans   = (const float*)d_in[1];
    const int*   lengths = (const int*)d_in[2];
    float* out = (float*)d_out;

    const int B = in_sizes[2];          // 256
    float* gv = (float*)d_ws;           // [B][128] raw E*f_m
    float* pv = gv + (size_t)B * NS;    // [B][128] p_m
    float* cf = pv + (size_t)B * NS;    // [B]
    float* cb = cf + B;                 // [B]

    crf_half<<<dim3(2 * (B / BT)), dim3(256), 0, stream>>>(unary, trans, lengths, gv, pv, cf, cb);
    crf_combine<<<dim3(B), dim3(64), 0, stream>>>(gv, pv, cf, cb, out);
}